// Round 4
// baseline (6438.874 us; speedup 1.0000x reference)
//
#include <hip/hip_runtime.h>
#include <hip/hip_bf16.h>

// Problem constants
#define BB 32    // batch
#define TT 128   // T_E == T_D
#define HH 256   // hidden
#define NROW 1024  // 4 gates * 256 units

__device__ __forceinline__ float sigmoid_f(float x) {
    return 1.f / (1.f + __expf(-x));
}
__device__ __forceinline__ float tanh_f(float x) {
    float e = __expf(2.f * x);
    return 1.f - 2.f / (e + 1.f);
}

// ---------------------------------------------------------------------------
// Prep: transpose We, Wd (256x256), tiled+coalesced.
// ---------------------------------------------------------------------------
__global__ __launch_bounds__(256) void prep_transpose(
    const float* __restrict__ We, const float* __restrict__ Wd,
    float* __restrict__ WeT, float* __restrict__ WdT) {
    __shared__ float t[64][65];
    const int m = blockIdx.x >> 4;
    const int tile = blockIdx.x & 15;
    const float* S = m ? Wd : We;
    float* D = m ? WdT : WeT;
    const int r0 = (tile >> 2) * 64, c0 = (tile & 3) * 64;
    const int lr = threadIdx.x >> 4;
    const int lc = threadIdx.x & 15;
    for (int rr = lr; rr < 64; rr += 16)
        *(float4*)&t[rr][lc * 4] = *(const float4*)&S[(r0 + rr) * HH + c0 + lc * 4];
    __syncthreads();
    for (int rr = lr; rr < 64; rr += 16) {
        float4 v;
        v.x = t[lc * 4 + 0][rr];
        v.y = t[lc * 4 + 1][rr];
        v.z = t[lc * 4 + 2][rr];
        v.w = t[lc * 4 + 3][rr];
        *(float4*)&D[(c0 + rr) * HH + r0 + lc * 4] = v;
    }
}

// ---------------------------------------------------------------------------
// LSTM: encoder (128 steps) then decoder (128 steps).
// ONE BLOCK PER BATCH (1024 threads, 16 waves, one CU). Each thread owns one
// full gate row: Whh[row][0..256) in 64 float4 registers (~256 regs, unified
// VGPR/AGPR file). All synchronization is __syncthreads() -- no cross-block
// mailbox, no agent-scope RTT on the critical path. h broadcast via LDS
// (same-address reads across all lanes = free broadcast).
// ---------------------------------------------------------------------------
__global__ __launch_bounds__(1024) void lstm_kernel(
    const float* __restrict__ seq,     // [B][128]
    const int* __restrict__ seq_m,     // [B]
    const float* __restrict__ target,  // [B][128]
    const float* __restrict__ Wih_e,   // [1024]
    const float* __restrict__ Whh_e,   // [1024][256]
    const float* __restrict__ bih_e, const float* __restrict__ bhh_e,
    const float* __restrict__ Wih_d, const float* __restrict__ Whh_d,
    const float* __restrict__ bih_d, const float* __restrict__ bhh_d,
    float* __restrict__ e_out,  // [B][128][256]
    float* __restrict__ d_out)  // [B][128][256]
{
    const int b = blockIdx.x;
    const int tid = threadIdx.x;   // == gate row (gate*256 + unit)
    const int unit = tid & 255;    // for phase 2 (tid < 256)
    const int last = seq_m[b] - 1;

    __shared__ float h_lds[HH];
    __shared__ float g_lds[NROW];
    __shared__ float x_lds[2 * TT];

    // stage x for all 256 steps
    if (tid < TT) {
        x_lds[tid] = seq[b * TT + tid];
        x_lds[TT + tid] = target[b * TT + tid];
    }

    float4 w[64];
    float bias_r, wih_r;
    auto loadw = [&](const float* Whh, const float* Wih,
                     const float* bih, const float* bhh) {
        const float4* wr = (const float4*)(Whh + tid * HH);
#pragma unroll
        for (int i = 0; i < 64; ++i) w[i] = wr[i];
        bias_r = bih[tid] + bhh[tid];
        wih_r = Wih[tid];
    };
    loadw(Whh_e, Wih_e, bih_e, bhh_e);

    if (tid < 64) ((float4*)h_lds)[tid] = make_float4(0.f, 0.f, 0.f, 0.f);
    __syncthreads();

    float c = 0.f, c_saved = 0.f, h_saved = 0.f;

    for (int t = 0; t < 2 * TT; ++t) {
        const int phase = t >> 7;  // 0 = encoder, 1 = decoder
        const int tt = t & 127;
        const float x = x_lds[t];

        // ---- phase 1: full gate-row dot product (k = 256) ----
        const float4* h4 = (const float4*)h_lds;
        float4 a4 = make_float4(0.f, 0.f, 0.f, 0.f);
#pragma unroll
        for (int i = 0; i < 64; ++i) {
            float4 hv = h4[i];  // same address across lanes -> LDS broadcast
            a4.x = fmaf(w[i].x, hv.x, a4.x);
            a4.y = fmaf(w[i].y, hv.y, a4.y);
            a4.z = fmaf(w[i].z, hv.z, a4.z);
            a4.w = fmaf(w[i].w, hv.w, a4.w);
        }
        g_lds[tid] = ((a4.x + a4.y) + (a4.z + a4.w)) + bias_r + x * wih_r;
        __syncthreads();  // (A) gates visible; h_lds free to overwrite

        // ---- phase 2 (threads 0..255): nonlinearities, h update ----
        if (tid < 256) {
            float gi = g_lds[unit];
            float gf = g_lds[256 + unit];
            float gg = g_lds[512 + unit];
            float go = g_lds[768 + unit];
            float si = sigmoid_f(gi);
            float sf = sigmoid_f(gf);
            float tg = tanh_f(gg);
            float so = sigmoid_f(go);
            c = sf * c + si * tg;
            float h = so * tanh_f(c);
            if (phase == 0 && tt == last) {
                c_saved = c;
                h_saved = h;
            }
            h_lds[unit] = (t == TT - 1) ? h_saved : h;
            (phase ? d_out : e_out)[(b * TT + tt) * HH + unit] = h;
        }
        __syncthreads();  // (B) h_lds complete for next step

        if (t == TT - 1) {  // encoder -> decoder transition
            loadw(Whh_d, Wih_d, bih_d, bhh_d);
            if (tid < 256) c = c_saved;
        }
    }
}

// ---------------------------------------------------------------------------
// Projections: e2 = e @ We^T + be ; d2 = d @ Wd^T + bd.
// ---------------------------------------------------------------------------
__global__ __launch_bounds__(256) void proj_kernel(
    const float* __restrict__ e_in, const float* __restrict__ d_in,
    const float* __restrict__ WeT, const float* __restrict__ WdT,
    const float* __restrict__ be, const float* __restrict__ bd,
    float* __restrict__ e2, float* __restrict__ d2) {
    __shared__ float tile[16][HH];
    const int blk = blockIdx.x;
    const bool isd = blk >= 256;
    const float* in = isd ? d_in : e_in;
    const float* WT = isd ? WdT : WeT;
    const float* bias = isd ? bd : be;
    float* out = isd ? d2 : e2;
    const int r0 = (isd ? blk - 256 : blk) * 16;
    const int tid = threadIdx.x;

    {
        const float4* src = (const float4*)(in + r0 * HH);
        float4* dst = (float4*)(&tile[0][0]);
        for (int idx = tid; idx < 16 * 64; idx += 256) dst[idx] = src[idx];
    }
    __syncthreads();

    float acc[16];
#pragma unroll
    for (int r = 0; r < 16; ++r) acc[r] = 0.f;
    const int cidx = tid;
    for (int k = 0; k < HH; k += 4) {
        float w0 = WT[(k + 0) * HH + cidx];
        float w1 = WT[(k + 1) * HH + cidx];
        float w2 = WT[(k + 2) * HH + cidx];
        float w3 = WT[(k + 3) * HH + cidx];
#pragma unroll
        for (int r = 0; r < 16; ++r) {
            float4 iv = *(const float4*)&tile[r][k];  // LDS broadcast
            acc[r] = fmaf(iv.x, w0, acc[r]);
            acc[r] = fmaf(iv.y, w1, acc[r]);
            acc[r] = fmaf(iv.z, w2, acc[r]);
            acc[r] = fmaf(iv.w, w3, acc[r]);
        }
    }
    const float bb = bias[cidx];
#pragma unroll
    for (int r = 0; r < 16; ++r) out[(r0 + r) * HH + cidx] = acc[r] + bb;
}

// ---------------------------------------------------------------------------
// Attention + mask + softmax.
// ---------------------------------------------------------------------------
#define EPAD 260
__global__ __launch_bounds__(256) void attn_kernel(
    const float* __restrict__ e2, const float* __restrict__ d2,
    const float* __restrict__ vv, const float* __restrict__ seq,
    float* __restrict__ out) {
    __shared__ float e2c[32][EPAD];
    __shared__ float d2t[8][EPAD];
    __shared__ float p_lds[8][128];
    __shared__ float v_lds[HH];

    const int blk = blockIdx.x;
    const int b = blk >> 4;
    const int i0 = (blk & 15) * 8;
    const int tid = threadIdx.x;
    const int jl = tid & 31, ii = tid >> 5;

    if (tid < 64) *(float4*)&v_lds[tid * 4] = ((const float4*)vv)[tid];
    for (int idx = tid; idx < 8 * 64; idx += 256) {
        int r = idx >> 6, q = idx & 63;
        *(float4*)&d2t[r][q * 4] = ((const float4*)(d2 + (b * TT + i0 + r) * HH))[q];
    }

    for (int jc = 0; jc < TT; jc += 32) {
        __syncthreads();
        for (int idx = tid; idx < 32 * 64; idx += 256) {
            int r = idx >> 6, q = idx & 63;
            *(float4*)&e2c[r][q * 4] = ((const float4*)(e2 + (b * TT + jc + r) * HH))[q];
        }
        __syncthreads();

        float acc = 0.f;
        for (int h = 0; h < HH; h += 4) {
            float4 ev = *(const float4*)&e2c[jl][h];
            float4 dv = *(const float4*)&d2t[ii][h];
            float4 vx = *(const float4*)&v_lds[h];
            acc = fmaf(tanh_f(ev.x + dv.x), vx.x, acc);
            acc = fmaf(tanh_f(ev.y + dv.y), vx.y, acc);
            acc = fmaf(tanh_f(ev.z + dv.z), vx.z, acc);
            acc = fmaf(tanh_f(ev.w + dv.w), vx.w, acc);
        }
        const int j = jc + jl;
        float sv = (j == 0) ? 0.1f : seq[b * TT + j];
        if (sv == 0.f) acc -= 1000.f;
        p_lds[ii][j] = acc;
    }
    __syncthreads();

    const int gr = tid >> 5, l = tid & 31;
    float x0 = p_lds[gr][l], x1 = p_lds[gr][l + 32];
    float x2 = p_lds[gr][l + 64], x3 = p_lds[gr][l + 96];
    float m = fmaxf(fmaxf(x0, x1), fmaxf(x2, x3));
#pragma unroll
    for (int o = 16; o >= 1; o >>= 1) m = fmaxf(m, __shfl_xor(m, o));
    float q0 = __expf(x0 - m), q1 = __expf(x1 - m);
    float q2 = __expf(x2 - m), q3 = __expf(x3 - m);
    float s = (q0 + q1) + (q2 + q3);
#pragma unroll
    for (int o = 16; o >= 1; o >>= 1) s += __shfl_xor(s, o);
    float inv = 1.f / s;
    float* orow = out + (b * TT + i0 + gr) * TT;
    orow[l] = q0 * inv;
    orow[l + 32] = q1 * inv;
    orow[l + 64] = q2 * inv;
    orow[l + 96] = q3 * inv;
}

// ---------------------------------------------------------------------------
extern "C" void kernel_launch(void* const* d_in, const int* in_sizes, int n_in,
                              void* d_out, int out_size, void* d_ws, size_t ws_size,
                              hipStream_t stream) {
    const float* seq = (const float*)d_in[0];
    const int* seq_m = (const int*)d_in[1];
    const float* target = (const float*)d_in[2];
    const float* Wih_e = (const float*)d_in[3];
    const float* Whh_e = (const float*)d_in[4];
    const float* bih_e = (const float*)d_in[5];
    const float* bhh_e = (const float*)d_in[6];
    const float* Wih_d = (const float*)d_in[7];
    const float* Whh_d = (const float*)d_in[8];
    const float* bih_d = (const float*)d_in[9];
    const float* bhh_d = (const float*)d_in[10];
    const float* We = (const float*)d_in[11];
    const float* be = (const float*)d_in[12];
    const float* Wd = (const float*)d_in[13];
    const float* bd = (const float*)d_in[14];
    const float* vv = (const float*)d_in[15];

    float* ws = (float*)d_ws;
    const size_t SZ_ED = (size_t)BB * TT * HH;  // 1,048,576 floats
    float* e_buf = ws;
    float* d_buf = e_buf + SZ_ED;
    float* e2 = d_buf + SZ_ED;
    float* d2 = e2 + SZ_ED;
    float* WeT = d2 + SZ_ED;
    float* WdT = WeT + HH * HH;

    const size_t needed = (4 * SZ_ED + 2 * HH * HH) * sizeof(float);
    if (ws_size < needed) return;

    prep_transpose<<<32, 256, 0, stream>>>(We, Wd, WeT, WdT);
    lstm_kernel<<<BB, 1024, 0, stream>>>(seq, seq_m, target, Wih_e, Whh_e, bih_e,
                                         bhh_e, Wih_d, Whh_d, bih_d, bhh_d, e_buf,
                                         d_buf);
    proj_kernel<<<512, 256, 0, stream>>>(e_buf, d_buf, WeT, WdT, be, bd, e2, d2);
    attn_kernel<<<512, 256, 0, stream>>>(e2, d2, vv, seq, (float*)d_out);
}

// Round 6
// 808.947 us; speedup vs baseline: 7.9596x; 7.9596x over previous
//
#include <hip/hip_runtime.h>
#include <hip/hip_bf16.h>

// Problem constants
#define BB 32    // batch
#define TT 128   // T_E == T_D
#define HH 256   // hidden
#define G4 4     // blocks per batch for LSTM
#define UPB 64   // units per LSTM block (256/4)
#define RPB 256  // gate rows per LSTM block (4 gates * 64 units)

#define AGENT __HIP_MEMORY_SCOPE_AGENT

__device__ __forceinline__ float sigmoid_f(float x) {
    return 1.f / (1.f + __expf(-x));
}
__device__ __forceinline__ float tanh_f(float x) {
    float e = __expf(2.f * x);
    return 1.f - 2.f / (e + 1.f);
}

// ---------------------------------------------------------------------------
// Prep: transpose We, Wd (256x256), tiled+coalesced.
// ---------------------------------------------------------------------------
__global__ __launch_bounds__(256) void prep_transpose(
    const float* __restrict__ We, const float* __restrict__ Wd,
    float* __restrict__ WeT, float* __restrict__ WdT) {
    __shared__ float t[64][65];
    const int m = blockIdx.x >> 4;
    const int tile = blockIdx.x & 15;
    const float* S = m ? Wd : We;
    float* D = m ? WdT : WeT;
    const int r0 = (tile >> 2) * 64, c0 = (tile & 3) * 64;
    const int lr = threadIdx.x >> 4;
    const int lc = threadIdx.x & 15;
    for (int rr = lr; rr < 64; rr += 16)
        *(float4*)&t[rr][lc * 4] = *(const float4*)&S[(r0 + rr) * HH + c0 + lc * 4];
    __syncthreads();
    for (int rr = lr; rr < 64; rr += 16) {
        float4 v;
        v.x = t[lc * 4 + 0][rr];
        v.y = t[lc * 4 + 1][rr];
        v.z = t[lc * 4 + 2][rr];
        v.w = t[lc * 4 + 3][rr];
        *(float4*)&D[(c0 + rr) * HH + r0 + lc * 4] = v;
    }
}

// ---------------------------------------------------------------------------
// LSTM (R3 tagged-mailbox structure, hang-proof dual-path publish/poll).
// grid = 128 blocks, mapping blk = g*32 + b so the 4 partner blocks of batch b
// are {b, b+32, b+64, b+96} -> likely same XCD under the blk%8 round-robin
// dispatch heuristic (speed hint only, never a correctness dependency).
//
// Publish: sc0 (SE-scope, L2-write-through) store of the tagged packet, THEN a
// relaxed agent-scope atomic store of the IDENTICAL packet (R3's proven path).
// Same address + same bytes -> completion order irrelevant.
// Poll: sc0 loads (fast if served by the shared XCD L2), with every 8th
// iteration a relaxed agent-scope atomic load. Forward progress is guaranteed
// by the atomic path regardless of sc0 cache behavior -> cannot hang.
// Tag-in-data (u64 = tag<<32 | float bits), monotonic tags, ping-pong slot;
// slot-reuse safety by the R3 causal-chain argument.
// ---------------------------------------------------------------------------
__global__ __launch_bounds__(512, 2) void lstm_kernel(
    const float* __restrict__ seq,     // [B][128]
    const int* __restrict__ seq_m,     // [B]
    const float* __restrict__ target,  // [B][128]
    const float* __restrict__ Wih_e,   // [1024]
    const float* __restrict__ Whh_e,   // [1024][256]
    const float* __restrict__ bih_e, const float* __restrict__ bhh_e,
    const float* __restrict__ Wih_d, const float* __restrict__ Whh_d,
    const float* __restrict__ bih_d, const float* __restrict__ bhh_d,
    float* __restrict__ e_out,  // [B][128][256]
    float* __restrict__ d_out,  // [B][128][256]
    unsigned long long* __restrict__ mbox,   // [2][B][256] tagged h packets
    unsigned long long* __restrict__ hsave)  // [B][256] tag-1 enc state @ last
{
    const int blk = blockIdx.x;
    const int b = blk & 31;   // batch
    const int g = blk >> 5;   // group slice 0..3
    const int tid = threadIdx.x;
    const int row_local = tid >> 1;  // 0..255
    const int half = tid & 1;        // k-half
    const int gate = row_local >> 6; // 0..3 (i,f,g,o)
    const int u_local = row_local & 63;
    const int row_global = gate * HH + g * UPB + u_local;
    const int last = seq_m[b] - 1;

    __shared__ float h_lds[HH];
    __shared__ float g_lds[RPB];
    __shared__ float x_lds[2 * TT];

    for (int i = tid; i < TT; i += 512) {
        x_lds[i] = seq[b * TT + i];
        x_lds[TT + i] = target[b * TT + i];
    }

    float4 w[32];
    float bias_r, wih_r;
    auto loadw = [&](const float* Whh, const float* Wih,
                     const float* bih, const float* bhh) {
        const float4* wr = (const float4*)(Whh + row_global * HH + half * 128);
#pragma unroll
        for (int i = 0; i < 32; ++i) w[i] = wr[i];
        bias_r = bih[row_global] + bhh[row_global];
        wih_r = Wih[row_global];
    };
    loadw(Whh_e, Wih_e, bih_e, bhh_e);

    if (tid < 64) ((float4*)h_lds)[tid] = make_float4(0.f, 0.f, 0.f, 0.f);
    __syncthreads();

    float c = 0.f, c_saved = 0.f, h_saved = 0.f;

    for (int t = 0; t < 2 * TT; ++t) {
        const int phase = t >> 7;  // 0 = encoder, 1 = decoder
        const int tt = t & 127;
        const float x = x_lds[t];

        // ---- phase 1: gate-row dot product over own 128-wide k-slice ----
        const float4* h4 = ((const float4*)h_lds) + half * 32;
        float4 a4 = make_float4(0.f, 0.f, 0.f, 0.f);
#pragma unroll
        for (int i = 0; i < 32; ++i) {
            float4 hv = h4[i];
            a4.x = fmaf(w[i].x, hv.x, a4.x);
            a4.y = fmaf(w[i].y, hv.y, a4.y);
            a4.z = fmaf(w[i].z, hv.z, a4.z);
            a4.w = fmaf(w[i].w, hv.w, a4.w);
        }
        float acc = (a4.x + a4.y) + (a4.z + a4.w);
        acc += __shfl_xor(acc, 1);  // combine the two k-halves
        float gv = acc + bias_r + x * wih_r;
        if (half == 0) g_lds[row_local] = gv;
        __syncthreads();  // (A) gates visible; h_lds free to overwrite

        // ---- phase 2 (wave 0): nonlinearities, dual-publish tagged h ----
        if (tid < 64) {
            float gi = g_lds[tid];
            float gf = g_lds[64 + tid];
            float gg = g_lds[128 + tid];
            float go = g_lds[192 + tid];
            float si = sigmoid_f(gi);
            float sf = sigmoid_f(gf);
            float tg = tanh_f(gg);
            float so = sigmoid_f(go);
            c = sf * c + si * tg;
            float h = so * tanh_f(c);
            const int ug = g * UPB + tid;
            unsigned long long pkt =
                ((unsigned long long)(unsigned)(t + 1) << 32) | __float_as_uint(h);
            unsigned long long* dst = &mbox[(t & 1) * BB * HH + b * HH + ug];
            asm volatile("global_store_dwordx2 %0, %1, off sc0" ::"v"(dst), "v"(pkt)
                         : "memory");
            __hip_atomic_store(dst, pkt, __ATOMIC_RELAXED, AGENT);
            if (phase == 0 && tt == last) {
                c_saved = c;
                h_saved = h;
                unsigned long long spkt =
                    (1ull << 32) | (unsigned long long)__float_as_uint(h);
                unsigned long long* sdst = &hsave[b * HH + ug];
                asm volatile("global_store_dwordx2 %0, %1, off sc0" ::"v"(sdst),
                             "v"(spkt)
                             : "memory");
                __hip_atomic_store(sdst, spkt, __ATOMIC_RELAXED, AGENT);
            }
            h_lds[ug] = (t == TT - 1) ? h_saved : h;
            (phase ? d_out : e_out)[(b * TT + tt) * HH + ug] = h;
        }

        // ---- phase 3 (waves 1..3): hybrid poll of partners' tagged h ----
        if (tid >= 64 && tid < 256) {
            const int p = (g + (tid >> 6)) & 3;  // partner slice 1..3 away
            const int lane = tid & 63;
            const int pu = p * UPB + lane;
            unsigned long long* src;
            unsigned want;
            if (t == TT - 1) {
                src = &hsave[b * HH + pu];
                want = 1u;
            } else {
                src = &mbox[(t & 1) * BB * HH + b * HH + pu];
                want = (unsigned)(t + 1);
            }
            unsigned long long v;
            unsigned spin = 0;
            do {
                if ((++spin & 7u) == 0u) {
                    // guaranteed-visible path: progress cannot stall forever
                    v = __hip_atomic_load(src, __ATOMIC_RELAXED, AGENT);
                } else {
                    asm volatile(
                        "global_load_dwordx2 %0, %1, off sc0\n\t"
                        "s_waitcnt vmcnt(0)"
                        : "=v"(v)
                        : "v"(src)
                        : "memory");
                }
            } while ((unsigned)(v >> 32) != want);
            h_lds[pu] = __uint_as_float((unsigned)v);
        }
        __syncthreads();  // (B) h_lds complete for next step

        if (t == TT - 1) {  // encoder -> decoder transition
            loadw(Whh_d, Wih_d, bih_d, bhh_d);
            c = c_saved;
        }
    }
}

// ---------------------------------------------------------------------------
// Projections: e2 = e @ We^T + be ; d2 = d @ Wd^T + bd.
// ---------------------------------------------------------------------------
__global__ __launch_bounds__(256) void proj_kernel(
    const float* __restrict__ e_in, const float* __restrict__ d_in,
    const float* __restrict__ WeT, const float* __restrict__ WdT,
    const float* __restrict__ be, const float* __restrict__ bd,
    float* __restrict__ e2, float* __restrict__ d2) {
    __shared__ float tile[16][HH];
    const int blk = blockIdx.x;
    const bool isd = blk >= 256;
    const float* in = isd ? d_in : e_in;
    const float* WT = isd ? WdT : WeT;
    const float* bias = isd ? bd : be;
    float* out = isd ? d2 : e2;
    const int r0 = (isd ? blk - 256 : blk) * 16;
    const int tid = threadIdx.x;

    {
        const float4* src = (const float4*)(in + r0 * HH);
        float4* dst = (float4*)(&tile[0][0]);
        for (int idx = tid; idx < 16 * 64; idx += 256) dst[idx] = src[idx];
    }
    __syncthreads();

    float acc[16];
#pragma unroll
    for (int r = 0; r < 16; ++r) acc[r] = 0.f;
    const int cidx = tid;
    for (int k = 0; k < HH; k += 4) {
        float w0 = WT[(k + 0) * HH + cidx];
        float w1 = WT[(k + 1) * HH + cidx];
        float w2 = WT[(k + 2) * HH + cidx];
        float w3 = WT[(k + 3) * HH + cidx];
#pragma unroll
        for (int r = 0; r < 16; ++r) {
            float4 iv = *(const float4*)&tile[r][k];  // LDS broadcast
            acc[r] = fmaf(iv.x, w0, acc[r]);
            acc[r] = fmaf(iv.y, w1, acc[r]);
            acc[r] = fmaf(iv.z, w2, acc[r]);
            acc[r] = fmaf(iv.w, w3, acc[r]);
        }
    }
    const float bb = bias[cidx];
#pragma unroll
    for (int r = 0; r < 16; ++r) out[(r0 + r) * HH + cidx] = acc[r] + bb;
}

// ---------------------------------------------------------------------------
// Attention + mask + softmax.
// ---------------------------------------------------------------------------
#define EPAD 260
__global__ __launch_bounds__(256) void attn_kernel(
    const float* __restrict__ e2, const float* __restrict__ d2,
    const float* __restrict__ vv, const float* __restrict__ seq,
    float* __restrict__ out) {
    __shared__ float e2c[32][EPAD];
    __shared__ float d2t[8][EPAD];
    __shared__ float p_lds[8][128];
    __shared__ float v_lds[HH];

    const int blk = blockIdx.x;
    const int b = blk >> 4;
    const int i0 = (blk & 15) * 8;
    const int tid = threadIdx.x;
    const int jl = tid & 31, ii = tid >> 5;

    if (tid < 64) *(float4*)&v_lds[tid * 4] = ((const float4*)vv)[tid];
    for (int idx = tid; idx < 8 * 64; idx += 256) {
        int r = idx >> 6, q = idx & 63;
        *(float4*)&d2t[r][q * 4] = ((const float4*)(d2 + (b * TT + i0 + r) * HH))[q];
    }

    for (int jc = 0; jc < TT; jc += 32) {
        __syncthreads();
        for (int idx = tid; idx < 32 * 64; idx += 256) {
            int r = idx >> 6, q = idx & 63;
            *(float4*)&e2c[r][q * 4] = ((const float4*)(e2 + (b * TT + jc + r) * HH))[q];
        }
        __syncthreads();

        float acc = 0.f;
        for (int h = 0; h < HH; h += 4) {
            float4 ev = *(const float4*)&e2c[jl][h];
            float4 dv = *(const float4*)&d2t[ii][h];
            float4 vx = *(const float4*)&v_lds[h];
            acc = fmaf(tanh_f(ev.x + dv.x), vx.x, acc);
            acc = fmaf(tanh_f(ev.y + dv.y), vx.y, acc);
            acc = fmaf(tanh_f(ev.z + dv.z), vx.z, acc);
            acc = fmaf(tanh_f(ev.w + dv.w), vx.w, acc);
        }
        const int j = jc + jl;
        float sv = (j == 0) ? 0.1f : seq[b * TT + j];
        if (sv == 0.f) acc -= 1000.f;
        p_lds[ii][j] = acc;
    }
    __syncthreads();

    const int gr = tid >> 5, l = tid & 31;
    float x0 = p_lds[gr][l], x1 = p_lds[gr][l + 32];
    float x2 = p_lds[gr][l + 64], x3 = p_lds[gr][l + 96];
    float m = fmaxf(fmaxf(x0, x1), fmaxf(x2, x3));
#pragma unroll
    for (int o = 16; o >= 1; o >>= 1) m = fmaxf(m, __shfl_xor(m, o));
    float q0 = __expf(x0 - m), q1 = __expf(x1 - m);
    float q2 = __expf(x2 - m), q3 = __expf(x3 - m);
    float s = (q0 + q1) + (q2 + q3);
#pragma unroll
    for (int o = 16; o >= 1; o >>= 1) s += __shfl_xor(s, o);
    float inv = 1.f / s;
    float* orow = out + (b * TT + i0 + gr) * TT;
    orow[l] = q0 * inv;
    orow[l + 32] = q1 * inv;
    orow[l + 64] = q2 * inv;
    orow[l + 96] = q3 * inv;
}

// ---------------------------------------------------------------------------
extern "C" void kernel_launch(void* const* d_in, const int* in_sizes, int n_in,
                              void* d_out, int out_size, void* d_ws, size_t ws_size,
                              hipStream_t stream) {
    const float* seq = (const float*)d_in[0];
    const int* seq_m = (const int*)d_in[1];
    const float* target = (const float*)d_in[2];
    const float* Wih_e = (const float*)d_in[3];
    const float* Whh_e = (const float*)d_in[4];
    const float* bih_e = (const float*)d_in[5];
    const float* bhh_e = (const float*)d_in[6];
    const float* Wih_d = (const float*)d_in[7];
    const float* Whh_d = (const float*)d_in[8];
    const float* bih_d = (const float*)d_in[9];
    const float* bhh_d = (const float*)d_in[10];
    const float* We = (const float*)d_in[11];
    const float* be = (const float*)d_in[12];
    const float* Wd = (const float*)d_in[13];
    const float* bd = (const float*)d_in[14];
    const float* vv = (const float*)d_in[15];

    float* ws = (float*)d_ws;
    const size_t SZ_ED = (size_t)BB * TT * HH;  // 1,048,576 floats
    float* e_buf = ws;
    float* d_buf = e_buf + SZ_ED;
    float* e2 = d_buf + SZ_ED;
    float* d2 = e2 + SZ_ED;
    float* WeT = d2 + SZ_ED;
    float* WdT = WeT + HH * HH;
    unsigned long long* mbox = (unsigned long long*)(WdT + HH * HH);  // [2][B][H]
    unsigned long long* hsave = mbox + 2 * BB * HH;                   // [B][H]

    const size_t needed = (4 * SZ_ED + 2 * HH * HH) * sizeof(float) +
                          3 * BB * HH * sizeof(unsigned long long);
    if (ws_size < needed) return;

    hipMemsetAsync(mbox, 0, 3 * BB * HH * sizeof(unsigned long long), stream);
    prep_transpose<<<32, 256, 0, stream>>>(We, Wd, WeT, WdT);
    lstm_kernel<<<BB * G4, 512, 0, stream>>>(seq, seq_m, target, Wih_e, Whh_e, bih_e,
                                             bhh_e, Wih_d, Whh_d, bih_d, bhh_d, e_buf,
                                             d_buf, mbox, hsave);
    proj_kernel<<<512, 256, 0, stream>>>(e_buf, d_buf, WeT, WdT, be, bd, e2, d2);
    attn_kernel<<<512, 256, 0, stream>>>(e2, d2, vv, seq, (float*)d_out);
}

// Round 7
// 671.530 us; speedup vs baseline: 9.5884x; 1.2046x over previous
//
#include <hip/hip_runtime.h>
#include <hip/hip_bf16.h>

// Problem constants
#define BB 32    // batch
#define TT 128   // T_E == T_D
#define HH 256   // hidden
#define G4 4     // blocks per batch for LSTM
#define UPB 64   // units per LSTM block (256/4)
#define RPB 256  // gate rows per LSTM block (4 gates * 64 units)

#define AGENT __HIP_MEMORY_SCOPE_AGENT
#define AL(p) __hip_atomic_load((p), __ATOMIC_RELAXED, AGENT)

__device__ __forceinline__ float sigmoid_f(float x) {
    return 1.f / (1.f + __expf(-x));
}
__device__ __forceinline__ float tanh_f(float x) {
    float e = __expf(2.f * x);
    return 1.f - 2.f / (e + 1.f);
}

// ---------------------------------------------------------------------------
// Prep: transpose We, Wd (256x256), tiled+coalesced.
// ---------------------------------------------------------------------------
__global__ __launch_bounds__(256) void prep_transpose(
    const float* __restrict__ We, const float* __restrict__ Wd,
    float* __restrict__ WeT, float* __restrict__ WdT) {
    __shared__ float t[64][65];
    const int m = blockIdx.x >> 4;
    const int tile = blockIdx.x & 15;
    const float* S = m ? Wd : We;
    float* D = m ? WdT : WeT;
    const int r0 = (tile >> 2) * 64, c0 = (tile & 3) * 64;
    const int lr = threadIdx.x >> 4;
    const int lc = threadIdx.x & 15;
    for (int rr = lr; rr < 64; rr += 16)
        *(float4*)&t[rr][lc * 4] = *(const float4*)&S[(r0 + rr) * HH + c0 + lc * 4];
    __syncthreads();
    for (int rr = lr; rr < 64; rr += 16) {
        float4 v;
        v.x = t[lc * 4 + 0][rr];
        v.y = t[lc * 4 + 1][rr];
        v.z = t[lc * 4 + 2][rr];
        v.w = t[lc * 4 + 3][rr];
        *(float4*)&D[(c0 + rr) * HH + r0 + lc * 4] = v;
    }
}

// ---------------------------------------------------------------------------
// LSTM (R3 tagged-mailbox + pipelined 4-slot poll ring).
// grid = 128 blocks (blk = g*32 + b); block = 512 threads; weights in regs.
// Publish: ONE relaxed agent-scope atomic store of u64 (tag<<32 | float bits)
// -- the R3-proven visible path. Poll: 4 independent relaxed atomic loads kept
// in flight (prefill staggered ~192cyc by s_sleep) so the line is sampled
// ~every RTT/4 instead of once per RTT; checking the oldest slot only waits
// vmcnt(3) (compiler emits fine-grained waitcnt). Worst case (pessimistic
// waitcnt) == R3 behavior; every load is the guaranteed-visible path -> no
// hang mode. Monotonic tags + ping-pong slot; reuse-safety per R3 argument.
// ---------------------------------------------------------------------------
__global__ __launch_bounds__(512, 2) void lstm_kernel(
    const float* __restrict__ seq,     // [B][128]
    const int* __restrict__ seq_m,     // [B]
    const float* __restrict__ target,  // [B][128]
    const float* __restrict__ Wih_e,   // [1024]
    const float* __restrict__ Whh_e,   // [1024][256]
    const float* __restrict__ bih_e, const float* __restrict__ bhh_e,
    const float* __restrict__ Wih_d, const float* __restrict__ Whh_d,
    const float* __restrict__ bih_d, const float* __restrict__ bhh_d,
    float* __restrict__ e_out,  // [B][128][256]
    float* __restrict__ d_out,  // [B][128][256]
    unsigned long long* __restrict__ mbox,   // [2][B][256] tagged h packets
    unsigned long long* __restrict__ hsave)  // [B][256] tag-1 enc state @ last
{
    const int blk = blockIdx.x;
    const int b = blk & 31;   // batch
    const int g = blk >> 5;   // group slice 0..3
    const int tid = threadIdx.x;
    const int row_local = tid >> 1;  // 0..255
    const int half = tid & 1;        // k-half
    const int gate = row_local >> 6; // 0..3 (i,f,g,o)
    const int u_local = row_local & 63;
    const int row_global = gate * HH + g * UPB + u_local;
    const int last = seq_m[b] - 1;

    __shared__ float h_lds[HH];
    __shared__ float g_lds[RPB];
    __shared__ float x_lds[2 * TT];

    for (int i = tid; i < TT; i += 512) {
        x_lds[i] = seq[b * TT + i];
        x_lds[TT + i] = target[b * TT + i];
    }

    float4 w[32];
    float bias_r, wih_r;
    auto loadw = [&](const float* Whh, const float* Wih,
                     const float* bih, const float* bhh) {
        const float4* wr = (const float4*)(Whh + row_global * HH + half * 128);
#pragma unroll
        for (int i = 0; i < 32; ++i) w[i] = wr[i];
        bias_r = bih[row_global] + bhh[row_global];
        wih_r = Wih[row_global];
    };
    loadw(Whh_e, Wih_e, bih_e, bhh_e);

    if (tid < 64) ((float4*)h_lds)[tid] = make_float4(0.f, 0.f, 0.f, 0.f);
    __syncthreads();

    float c = 0.f, c_saved = 0.f, h_saved = 0.f;

    for (int t = 0; t < 2 * TT; ++t) {
        const int phase = t >> 7;  // 0 = encoder, 1 = decoder
        const int tt = t & 127;
        const float x = x_lds[t];

        // ---- phase 1: gate-row dot product over own 128-wide k-slice ----
        const float4* h4 = ((const float4*)h_lds) + half * 32;
        float4 a4 = make_float4(0.f, 0.f, 0.f, 0.f);
#pragma unroll
        for (int i = 0; i < 32; ++i) {
            float4 hv = h4[i];
            a4.x = fmaf(w[i].x, hv.x, a4.x);
            a4.y = fmaf(w[i].y, hv.y, a4.y);
            a4.z = fmaf(w[i].z, hv.z, a4.z);
            a4.w = fmaf(w[i].w, hv.w, a4.w);
        }
        float acc = (a4.x + a4.y) + (a4.z + a4.w);
        acc += __shfl_xor(acc, 1);  // combine the two k-halves
        float gv = acc + bias_r + x * wih_r;
        if (half == 0) g_lds[row_local] = gv;
        __syncthreads();  // (A) gates visible; h_lds free to overwrite

        // ---- phase 2 (wave 0): nonlinearities, publish tagged h ----
        if (tid < 64) {
            float gi = g_lds[tid];
            float gf = g_lds[64 + tid];
            float gg = g_lds[128 + tid];
            float go = g_lds[192 + tid];
            float si = sigmoid_f(gi);
            float sf = sigmoid_f(gf);
            float tg = tanh_f(gg);
            float so = sigmoid_f(go);
            c = sf * c + si * tg;
            float h = so * tanh_f(c);
            const int ug = g * UPB + tid;
            // publish FIRST: this store is the step's critical path
            unsigned long long pkt =
                ((unsigned long long)(unsigned)(t + 1) << 32) | __float_as_uint(h);
            __hip_atomic_store(&mbox[(t & 1) * BB * HH + b * HH + ug], pkt,
                               __ATOMIC_RELAXED, AGENT);
            if (phase == 0 && tt == last) {
                c_saved = c;
                h_saved = h;
                unsigned long long spkt =
                    (1ull << 32) | (unsigned long long)__float_as_uint(h);
                __hip_atomic_store(&hsave[b * HH + ug], spkt, __ATOMIC_RELAXED, AGENT);
            }
            h_lds[ug] = (t == TT - 1) ? h_saved : h;
            (phase ? d_out : e_out)[(b * TT + tt) * HH + ug] = h;
        }

        // ---- phase 3 (waves 1..3): pipelined-ring poll of partners' h ----
        if (tid >= 64 && tid < 256) {
            const int p = (g + (tid >> 6)) & 3;  // partner slice 1..3 away
            const int lane = tid & 63;
            const int pu = p * UPB + lane;
            unsigned long long* src;
            unsigned want;
            if (t == TT - 1) {
                src = &hsave[b * HH + pu];
                want = 1u;
            } else {
                src = &mbox[(t & 1) * BB * HH + b * HH + pu];
                want = (unsigned)(t + 1);
            }
            unsigned long long pv;
            {
                // staggered prefill: samples spaced ~RTT/4 apart
                unsigned long long r0 = AL(src);
                __builtin_amdgcn_s_sleep(3);
                unsigned long long r1 = AL(src);
                __builtin_amdgcn_s_sleep(3);
                unsigned long long r2 = AL(src);
                __builtin_amdgcn_s_sleep(3);
                unsigned long long r3 = AL(src);
                for (;;) {
                    if ((unsigned)(r0 >> 32) == want) { pv = r0; break; }
                    r0 = AL(src);
                    if ((unsigned)(r1 >> 32) == want) { pv = r1; break; }
                    r1 = AL(src);
                    if ((unsigned)(r2 >> 32) == want) { pv = r2; break; }
                    r2 = AL(src);
                    if ((unsigned)(r3 >> 32) == want) { pv = r3; break; }
                    r3 = AL(src);
                }
            }
            h_lds[pu] = __uint_as_float((unsigned)pv);
        }
        __syncthreads();  // (B) h_lds complete for next step

        if (t == TT - 1) {  // encoder -> decoder transition
            loadw(Whh_d, Wih_d, bih_d, bhh_d);
            c = c_saved;
        }
    }
}

// ---------------------------------------------------------------------------
// Projections: e2 = e @ We^T + be ; d2 = d @ Wd^T + bd.
// ---------------------------------------------------------------------------
__global__ __launch_bounds__(256) void proj_kernel(
    const float* __restrict__ e_in, const float* __restrict__ d_in,
    const float* __restrict__ WeT, const float* __restrict__ WdT,
    const float* __restrict__ be, const float* __restrict__ bd,
    float* __restrict__ e2, float* __restrict__ d2) {
    __shared__ float tile[16][HH];
    const int blk = blockIdx.x;
    const bool isd = blk >= 256;
    const float* in = isd ? d_in : e_in;
    const float* WT = isd ? WdT : WeT;
    const float* bias = isd ? bd : be;
    float* out = isd ? d2 : e2;
    const int r0 = (isd ? blk - 256 : blk) * 16;
    const int tid = threadIdx.x;

    {
        const float4* src = (const float4*)(in + r0 * HH);
        float4* dst = (float4*)(&tile[0][0]);
        for (int idx = tid; idx < 16 * 64; idx += 256) dst[idx] = src[idx];
    }
    __syncthreads();

    float acc[16];
#pragma unroll
    for (int r = 0; r < 16; ++r) acc[r] = 0.f;
    const int cidx = tid;
    for (int k = 0; k < HH; k += 4) {
        float w0 = WT[(k + 0) * HH + cidx];
        float w1 = WT[(k + 1) * HH + cidx];
        float w2 = WT[(k + 2) * HH + cidx];
        float w3 = WT[(k + 3) * HH + cidx];
#pragma unroll
        for (int r = 0; r < 16; ++r) {
            float4 iv = *(const float4*)&tile[r][k];  // LDS broadcast
            acc[r] = fmaf(iv.x, w0, acc[r]);
            acc[r] = fmaf(iv.y, w1, acc[r]);
            acc[r] = fmaf(iv.z, w2, acc[r]);
            acc[r] = fmaf(iv.w, w3, acc[r]);
        }
    }
    const float bb = bias[cidx];
#pragma unroll
    for (int r = 0; r < 16; ++r) out[(r0 + r) * HH + cidx] = acc[r] + bb;
}

// ---------------------------------------------------------------------------
// Attention + mask + softmax.
// ---------------------------------------------------------------------------
#define EPAD 260
__global__ __launch_bounds__(256) void attn_kernel(
    const float* __restrict__ e2, const float* __restrict__ d2,
    const float* __restrict__ vv, const float* __restrict__ seq,
    float* __restrict__ out) {
    __shared__ float e2c[32][EPAD];
    __shared__ float d2t[8][EPAD];
    __shared__ float p_lds[8][128];
    __shared__ float v_lds[HH];

    const int blk = blockIdx.x;
    const int b = blk >> 4;
    const int i0 = (blk & 15) * 8;
    const int tid = threadIdx.x;
    const int jl = tid & 31, ii = tid >> 5;

    if (tid < 64) *(float4*)&v_lds[tid * 4] = ((const float4*)vv)[tid];
    for (int idx = tid; idx < 8 * 64; idx += 256) {
        int r = idx >> 6, q = idx & 63;
        *(float4*)&d2t[r][q * 4] = ((const float4*)(d2 + (b * TT + i0 + r) * HH))[q];
    }

    for (int jc = 0; jc < TT; jc += 32) {
        __syncthreads();
        for (int idx = tid; idx < 32 * 64; idx += 256) {
            int r = idx >> 6, q = idx & 63;
            *(float4*)&e2c[r][q * 4] = ((const float4*)(e2 + (b * TT + jc + r) * HH))[q];
        }
        __syncthreads();

        float acc = 0.f;
        for (int h = 0; h < HH; h += 4) {
            float4 ev = *(const float4*)&e2c[jl][h];
            float4 dv = *(const float4*)&d2t[ii][h];
            float4 vx = *(const float4*)&v_lds[h];
            acc = fmaf(tanh_f(ev.x + dv.x), vx.x, acc);
            acc = fmaf(tanh_f(ev.y + dv.y), vx.y, acc);
            acc = fmaf(tanh_f(ev.z + dv.z), vx.z, acc);
            acc = fmaf(tanh_f(ev.w + dv.w), vx.w, acc);
        }
        const int j = jc + jl;
        float sv = (j == 0) ? 0.1f : seq[b * TT + j];
        if (sv == 0.f) acc -= 1000.f;
        p_lds[ii][j] = acc;
    }
    __syncthreads();

    const int gr = tid >> 5, l = tid & 31;
    float x0 = p_lds[gr][l], x1 = p_lds[gr][l + 32];
    float x2 = p_lds[gr][l + 64], x3 = p_lds[gr][l + 96];
    float m = fmaxf(fmaxf(x0, x1), fmaxf(x2, x3));
#pragma unroll
    for (int o = 16; o >= 1; o >>= 1) m = fmaxf(m, __shfl_xor(m, o));
    float q0 = __expf(x0 - m), q1 = __expf(x1 - m);
    float q2 = __expf(x2 - m), q3 = __expf(x3 - m);
    float s = (q0 + q1) + (q2 + q3);
#pragma unroll
    for (int o = 16; o >= 1; o >>= 1) s += __shfl_xor(s, o);
    float inv = 1.f / s;
    float* orow = out + (b * TT + i0 + gr) * TT;
    orow[l] = q0 * inv;
    orow[l + 32] = q1 * inv;
    orow[l + 64] = q2 * inv;
    orow[l + 96] = q3 * inv;
}

// ---------------------------------------------------------------------------
extern "C" void kernel_launch(void* const* d_in, const int* in_sizes, int n_in,
                              void* d_out, int out_size, void* d_ws, size_t ws_size,
                              hipStream_t stream) {
    const float* seq = (const float*)d_in[0];
    const int* seq_m = (const int*)d_in[1];
    const float* target = (const float*)d_in[2];
    const float* Wih_e = (const float*)d_in[3];
    const float* Whh_e = (const float*)d_in[4];
    const float* bih_e = (const float*)d_in[5];
    const float* bhh_e = (const float*)d_in[6];
    const float* Wih_d = (const float*)d_in[7];
    const float* Whh_d = (const float*)d_in[8];
    const float* bih_d = (const float*)d_in[9];
    const float* bhh_d = (const float*)d_in[10];
    const float* We = (const float*)d_in[11];
    const float* be = (const float*)d_in[12];
    const float* Wd = (const float*)d_in[13];
    const float* bd = (const float*)d_in[14];
    const float* vv = (const float*)d_in[15];

    float* ws = (float*)d_ws;
    const size_t SZ_ED = (size_t)BB * TT * HH;  // 1,048,576 floats
    float* e_buf = ws;
    float* d_buf = e_buf + SZ_ED;
    float* e2 = d_buf + SZ_ED;
    float* d2 = e2 + SZ_ED;
    float* WeT = d2 + SZ_ED;
    float* WdT = WeT + HH * HH;
    unsigned long long* mbox = (unsigned long long*)(WdT + HH * HH);  // [2][B][H]
    unsigned long long* hsave = mbox + 2 * BB * HH;                   // [B][H]

    const size_t needed = (4 * SZ_ED + 2 * HH * HH) * sizeof(float) +
                          3 * BB * HH * sizeof(unsigned long long);
    if (ws_size < needed) return;

    hipMemsetAsync(mbox, 0, 3 * BB * HH * sizeof(unsigned long long), stream);
    prep_transpose<<<32, 256, 0, stream>>>(We, Wd, WeT, WdT);
    lstm_kernel<<<BB * G4, 512, 0, stream>>>(seq, seq_m, target, Wih_e, Whh_e, bih_e,
                                             bhh_e, Wih_d, Whh_d, bih_d, bhh_d, e_buf,
                                             d_buf, mbox, hsave);
    proj_kernel<<<512, 256, 0, stream>>>(e_buf, d_buf, WeT, WdT, be, bd, e2, d2);
    attn_kernel<<<512, 256, 0, stream>>>(e2, d2, vv, seq, (float*)d_out);
}